// Round 5
// baseline (130.695 us; speedup 1.0000x reference)
//
#include <hip/hip_runtime.h>

// Medical2DSliceRenderer on MI355X (gfx950) — round 5: 4 px/lane
//
//   S1[c] = sum_g exp2(qa dx^2 + qb dx dy + qd dy^2 + log2(op*mask))  (= g*op)
//   S2[c] = sum_g (g*op)^2 * (ft/op)                                  (= g^2*op*ft)
//   img += (1-acc)*S2[c];  acc += (1-acc)*S1[c]
//
// Round 5: each lane renders FOUR pixels: cols {lane, lane+64} x rows {r, r+1}
// (two v2f pairs; dx shared across the row pair). One 32B scalar fetch per
// gaussian now feeds 256 px*g per wave (2x round 4) — attacks the measured
// correlation between scalar-feed bytes/iter and VALU stall (48%->66% busy
// when going 64B->32B). Block = 16 waves = 16 gaussian-splits of one
// (slice, row-pair); grid = 256 = 1 block/CU. Per-chunk LDS reduction
// (36KB, stride-9 floats -> bank-conflict-free); waves 0-3 carry img/acc.

#define EPSV 1e-6f
#define NG   4096
#define PP   16384
#define NSL  4
#define SPLIT 16
#define GPC  64          // gaussians per split per chunk (1024/16)

typedef float v2f __attribute__((ext_vector_type(2)));

static __device__ __forceinline__ v2f splat(float s) { v2f r; r.x = s; r.y = s; return r; }

__global__ void prep_kernel(const float* __restrict__ means,
                            const float* __restrict__ scales,
                            const float* __restrict__ rots,
                            const float* __restrict__ ops,
                            const float* __restrict__ fts,
                            float4* __restrict__ gdata) {
    __shared__ float red[256];
    int tid = threadIdx.x;

    float m = -1e30f;
    for (int i = tid; i < NG; i += 256) m = fmaxf(m, scales[i*3+2]);
    red[tid] = m;
    __syncthreads();
    for (int s = 128; s > 0; s >>= 1) {
        if (tid < s) red[tid] = fmaxf(red[tid], red[tid+s]);
        __syncthreads();
    }
    float maxd = 3.0f * red[0];

    int g = blockIdx.x * 256 + tid;
    if (g >= NG) return;

    float qw = rots[g*4+0], qx = rots[g*4+1], qy = rots[g*4+2], qz = rots[g*4+3];
    float inorm = rsqrtf(qw*qw + qx*qx + qy*qy + qz*qz);
    qw *= inorm; qx *= inorm; qy *= inorm; qz *= inorm;

    float s0 = scales[g*3+0], s1 = scales[g*3+1], s2 = scales[g*3+2];

    float r00 = 1.f - 2.f*(qy*qy + qz*qz), r01 = 2.f*(qx*qy - qw*qz), r02 = 2.f*(qx*qz + qw*qy);
    float r10 = 2.f*(qx*qy + qw*qz), r11 = 1.f - 2.f*(qx*qx + qz*qz), r12 = 2.f*(qy*qz - qw*qx);
    float r20 = 2.f*(qx*qz - qw*qy), r21 = 2.f*(qy*qz + qw*qx), r22 = 1.f - 2.f*(qx*qx + qy*qy);

    float a00 = r00*s0, a01 = r01*s1, a02 = r02*s2;
    float a10 = r10*s0, a11 = r11*s1, a12 = r12*s2;
    float a20 = r20*s0, a21 = r21*s1, a22 = r22*s2;

    float c00 = a00*a00 + a01*a01 + a02*a02;
    float c01 = a00*a10 + a01*a11 + a02*a12;
    float c02 = a00*a20 + a01*a21 + a02*a22;
    float c11 = a10*a10 + a11*a11 + a12*a12;
    float c12 = a10*a20 + a11*a21 + a12*a22;
    float c22 = a20*a20 + a21*a21 + a22*a22;

    float izz = 1.0f / (c22 + EPSV);
    float kx = c02 * izz, ky = c12 * izz;
    float sa = c00 - c02*c02*izz + EPSV;
    float sb = c01 - c02*c12*izz;
    float sd = c11 - c12*c12*izz + EPSV;
    float det = sa*sd - sb*sb;
    float idet = 1.0f / det;

    const float C0 = -0.72134752044448170f;   // -0.5 * log2(e)
    float qa = C0 * sd * idet;
    float qb = C0 * (-2.0f * sb * idet);
    float qd = C0 * sa * idet;

    float mx = means[g*3+0], my = means[g*3+1], mz = means[g*3+2];
    float op = ops[g], ft = fts[g];

    #pragma unroll
    for (int s = 0; s < NSL; ++s) {
        float z = -0.15f + 0.1f * (float)s;
        float zoff = z - mz;
        float m2x = mx + kx * zoff;
        float m2y = my + ky * zoff;
        bool live = (fabsf(mz - z) < maxd) && (op > 1e-12f);
        float lop  = live ? __log2f(op) : -__builtin_inff();
        float ftop = live ? ft / op     : 0.f;
        float4* o = gdata + ((size_t)(s*NG + g)) * 2;
        o[0] = make_float4(-m2x, -m2y, qa, qb);
        o[1] = make_float4( qd,   lop,  ftop, 0.f);
    }
}

__global__ __launch_bounds__(1024, 4)
void render_kernel(const float4* __restrict__ gdata, float* __restrict__ out) {
    __shared__ float parts[SPLIT][64][9];   // 36,864 B; stride-9 -> conflict-free

    int tid   = threadIdx.x;
    int lane  = tid & 63;
    int split = __builtin_amdgcn_readfirstlane(tid >> 6);   // 0..15, wave-uniform
    int slice = blockIdx.x >> 6;
    int r0    = (blockIdx.x & 63) * 2;

    const float DL = 2.0f / 127.0f;
    v2f xP;  xP.x = -1.0f + (float)lane * DL;  xP.y = xP.x + 64.0f * DL;
    v2f yP0 = splat(-1.0f + (float)r0 * DL);
    v2f yP1 = splat(-1.0f + (float)(r0 + 1) * DL);

    const float4* gs = gdata + (size_t)slice * NG * 2;

    float img = 0.f, acc = 0.f;    // live in waves 0..3 (px-slot = split)

    #pragma unroll
    for (int c = 0; c < 4; ++c) {
        const float4* p = gs + (size_t)(c * 1024 + split * GPC) * 2;  // uniform
        v2f a10 = {0.f,0.f}, a11 = {0.f,0.f}, a20 = {0.f,0.f}, a21 = {0.f,0.f};
        #pragma unroll 8
        for (int g = 0; g < GPC; ++g) {
            float4 A = p[2*g+0];           // -m2x, -m2y, qa, qb   (s_load)
            float4 B = p[2*g+1];           // qd, lop, ftop, pad
            v2f dx  = xP  + splat(A.x);    // shared across the row pair
            v2f dy0 = yP0 + splat(A.y);
            v2f dy1 = yP1 + splat(A.y);
            v2f t0  = __builtin_elementwise_fma(splat(A.z), dx, splat(A.w) * dy0);
            v2f t1  = __builtin_elementwise_fma(splat(A.z), dx, splat(A.w) * dy1);
            v2f e0  = __builtin_elementwise_fma(splat(B.x) * dy0, dy0, splat(B.y));
            v2f e1  = __builtin_elementwise_fma(splat(B.x) * dy1, dy1, splat(B.y));
            v2f mm0 = __builtin_elementwise_fma(dx, t0, e0);
            v2f mm1 = __builtin_elementwise_fma(dx, t1, e1);
            v2f gv0, gv1;
            gv0.x = __builtin_amdgcn_exp2f(mm0.x);
            gv0.y = __builtin_amdgcn_exp2f(mm0.y);
            gv1.x = __builtin_amdgcn_exp2f(mm1.x);
            gv1.y = __builtin_amdgcn_exp2f(mm1.y);
            a10 += gv0;
            a11 += gv1;
            a20 = __builtin_elementwise_fma(gv0 * gv0, splat(B.z), a20);
            a21 = __builtin_elementwise_fma(gv1 * gv1, splat(B.z), a21);
        }
        // BARRIER1: also guarantees waves 0..3 finished reading chunk c-1
        __syncthreads();
        parts[split][lane][0] = a10.x;   // S1 px-slot 0: (r0,   lane)
        parts[split][lane][1] = a10.y;   // S1 px-slot 1: (r0,   lane+64)
        parts[split][lane][2] = a11.x;   // S1 px-slot 2: (r0+1, lane)
        parts[split][lane][3] = a11.y;   // S1 px-slot 3: (r0+1, lane+64)
        parts[split][lane][4] = a20.x;   // S2 slots
        parts[split][lane][5] = a20.y;
        parts[split][lane][6] = a21.x;
        parts[split][lane][7] = a21.y;
        __syncthreads();
        if (split < 4) {                 // wave w reduces px-slot w
            float S1 = 0.f, S2 = 0.f;
            #pragma unroll
            for (int s = 0; s < SPLIT; ++s) {
                S1 += parts[s][lane][split];
                S2 += parts[s][lane][4 + split];
            }
            float om = 1.0f - acc;
            img = fmaf(om, S2, img);
            acc = fmaf(om, S1, acc);
        }
    }

    if (split < 4)
        out[slice * PP + (r0 + (split >> 1)) * 128 + (split & 1) * 64 + lane] = img;
}

extern "C" void kernel_launch(void* const* d_in, const int* in_sizes, int n_in,
                              void* d_out, int out_size, void* d_ws, size_t ws_size,
                              hipStream_t stream) {
    const float* means  = (const float*)d_in[0];
    const float* scales = (const float*)d_in[1];
    const float* rots   = (const float*)d_in[2];
    const float* ops    = (const float*)d_in[3];
    const float* fts    = (const float*)d_in[4];
    float* out = (float*)d_out;

    float4* gdata = (float4*)d_ws;   // 4*4096*32B = 512 KB

    prep_kernel<<<NG/256, 256, 0, stream>>>(means, scales, rots, ops, fts, gdata);
    render_kernel<<<NSL*64, 1024, 0, stream>>>(gdata, out);
}